// Round 18
// baseline (735.494 us; speedup 1.0000x reference)
//
#include <hip/hip_runtime.h>
#include <hip/hip_bf16.h>
#include <math.h>

// ---------------------------------------------------------------------------
// DeepSeekV3 MLA forward, bf16 MFMA pipeline.  Workspace: 237.0 MB (overlaid,
// plus d_out used as pre-o-proj scratch for the kv_b weight cast).
// B=2, S=2048, H=32, DN=128, DR=64, DV=128, HID=4096, QR=1536, KVR=512
// Fusions: q_a+kv_a+k_rope in one 4096^3 GEMM; q_b GEMM (BN=192, head-aligned)
// writes Qa layout; kv_b GEMM splits k_nope->Ka / V^T->global; RoPE rope-dims.
// One 7-way up-front cast (all weights + hs).  GEMM loop: 2 barriers/iter.
// Attention (r12): 16 q-rows/wave, 56 KB LDS, single-buffered K/V via gll16,
// 2 blocks/CU; softmax max/sum reduced via trees (v_max3-friendly).
// ---------------------------------------------------------------------------

typedef __attribute__((ext_vector_type(8))) short s16x8;   // 8 x bf16 (4 VGPR)
typedef __attribute__((ext_vector_type(4))) float f32x4;
typedef __attribute__((ext_vector_type(4))) unsigned short u16x4;

#define DEV __device__ __forceinline__

constexpr int Bc = 2, Sc = 2048, Tc = Bc * Sc;     // tokens = 4096
constexpr int Hc = 32, DNc = 128, DRc = 64, DVc = 128;
constexpr int HIDc = 4096, QRc = 1536, KVRc = 512;
constexpr int DQK = DNc + DRc;                      // 192

DEV unsigned short f2bf(float f) {
  unsigned u = __float_as_uint(f);
  return (unsigned short)((u + 0x7fffu + ((u >> 16) & 1u)) >> 16);
}
DEV float bf2f(unsigned short u) { return __uint_as_float(((unsigned)u) << 16); }

DEV void gll16(const void* g, void* l) {
  __builtin_amdgcn_global_load_lds((const __attribute__((address_space(1))) void*)g,
                                   (__attribute__((address_space(3))) void*)l, 16, 0, 0);
}
DEV f32x4 mfma_bf16(s16x8 a, s16x8 b, f32x4 c) {
  return __builtin_amdgcn_mfma_f32_16x16x32_bf16(a, b, c, 0, 0, 0);
}
DEV unsigned cvt_pk_bf16(float a, float b) {     // lo=bf16(a), hi=bf16(b)
  unsigned r;
  asm("v_cvt_pk_bf16_f32 %0, %1, %2" : "=v"(r) : "v"(a), "v"(b));
  return r;
}

// ---------------------------------------------------------------------------
// casts: 7-way merged variant covering every fp32->bf16 conversion up front
// ---------------------------------------------------------------------------
DEV void cast4(const float* src, unsigned short* dst, long i) {
  float4 v = *(const float4*)(src + i);
  u16x4 o;
  o.x = f2bf(v.x); o.y = f2bf(v.y); o.z = f2bf(v.z); o.w = f2bf(v.w);
  *(u16x4*)(dst + i) = o;
}

__global__ __launch_bounds__(256) void cast7_k(const float* s0, unsigned short* d0, long n0,
                                               const float* s1, unsigned short* d1, long n1,
                                               const float* s2, unsigned short* d2, long n2,
                                               const float* s3, unsigned short* d3, long n3,
                                               const float* s4, unsigned short* d4, long n4,
                                               const float* s5, unsigned short* d5, long n5,
                                               const float* s6, unsigned short* d6, long n6) {
  long i = ((long)blockIdx.x * 256 + threadIdx.x) * 4;
  if (i < n0) { cast4(s0, d0, i); return; }  i -= n0;
  if (i < n1) { cast4(s1, d1, i); return; }  i -= n1;
  if (i < n2) { cast4(s2, d2, i); return; }  i -= n2;
  if (i < n3) { cast4(s3, d3, i); return; }  i -= n3;
  if (i < n4) { cast4(s4, d4, i); return; }  i -= n4;
  if (i < n5) { cast4(s5, d5, i); return; }  i -= n5;
  if (i < n6) { cast4(s6, d6, i); }
}

// ---------------------------------------------------------------------------
// RMSNorm helper + merged kernel (q rows then kv rows, pitch HIDc)
// ---------------------------------------------------------------------------
template <int COLS>
DEV void rms_row(unsigned short* p, const float* __restrict__ w, float* sred) {
  float ss = 0.f;
  for (int c = threadIdx.x * 8; c < COLS; c += 2048) {
    s16x8 v = *(const s16x8*)&p[c];
    #pragma unroll
    for (int j = 0; j < 8; ++j) { const float f = bf2f((unsigned short)v[j]); ss += f * f; }
  }
  #pragma unroll
  for (int off = 1; off < 64; off <<= 1) ss += __shfl_xor(ss, off, 64);
  if ((threadIdx.x & 63) == 0) sred[threadIdx.x >> 6] = ss;
  __syncthreads();
  const float inv = rsqrtf((sred[0] + sred[1] + sred[2] + sred[3]) / (float)COLS + 1e-6f);
  for (int c = threadIdx.x * 8; c < COLS; c += 2048) {
    s16x8 v = *(const s16x8*)&p[c];
    s16x8 o;
    #pragma unroll
    for (int j = 0; j < 8; ++j)
      o[j] = (short)f2bf(bf2f((unsigned short)v[j]) * inv * w[c + j]);
    *(s16x8*)&p[c] = o;
  }
}

__global__ __launch_bounds__(256) void rmsnorm2_k(unsigned short* __restrict__ cbuf,
                                                  const float* __restrict__ wq,
                                                  const float* __restrict__ wkv) {
  __shared__ float sred[4];
  const int bid = blockIdx.x;
  if (bid < Tc) rms_row<QRc>(cbuf + (size_t)bid * HIDc, wq, sred);
  else          rms_row<KVRc>(cbuf + (size_t)(bid - Tc) * HIDc + QRc, wkv, sred);
}

// ---------------------------------------------------------------------------
// GEMM: C[M,N] = A[M,K](bf16, row pitch lda) * B[N,K]^T(bf16, pitch K).
// BM=256 x BN(256 or 192) tile, BK=64.  512 thr = 8 waves (2M x 4N).
// Counted-vmcnt double-buffer.  TWO barriers per iter (RAW post-vmcnt + WAR
// end); quadrant groups share one K-tile buffer -> no inner barriers.
// LDS swizzle via pre-swizzled gll16 SOURCE, XOR (row&7)<<3.
// MODE: 0 = bf16 linear, 1 = f32 linear,
//       2 = Qa layout   (row=token, col=h*192+d  -> Qa[bh][s][192])
//       3 = kv split    (col=h*256+c: c<128 -> Ka[bh][s][192];
//                        c>=128 -> V^T global [bh][dv][s], 8B packed stores)
// ---------------------------------------------------------------------------
template <int MODE, int BN = 256>
__global__ __launch_bounds__(512, 2) void gemm256_bt(const unsigned short* __restrict__ A,
                                                     int lda,
                                                     const unsigned short* __restrict__ B,
                                                     void* __restrict__ Cout,
                                                     void* __restrict__ Cout2,
                                                     int M, int N, int K) {
  constexpr int NFR = BN / 64;                  // n-frags per wave (4 or 3)
  constexpr int NB2 = NFR - 2;                  // frags in the "b2" group (2 or 1)
  __shared__ unsigned short As[2][256 * 64];    // 64 KB
  __shared__ unsigned short Bs[2][BN * 64];     // 64 or 48 KB
  const int tid = threadIdx.x;
  const int wv = tid >> 6, l = tid & 63;
  const int lo = l & 15, hi = l >> 4;
  const int wm = wv >> 2, wn = wv & 3;          // wave grid 2 x 4
  // bijective XCD swizzle (m204)
  const int nbx = N / BN;
  const int nwg = (M >> 8) * nbx;
  const int orig = blockIdx.x;
  const int q8 = nwg >> 3, r8 = nwg & 7, xc = orig & 7, o8 = orig >> 3;
  const int wg = (xc < r8 ? xc * (q8 + 1) : r8 * (q8 + 1) + (xc - r8) * q8) + o8;
  const int bx = wg % nbx, by = wg / nbx;
  const int m0 = by * 256, n0 = bx * BN;
  const int lrow = l >> 3;                       // row within 8-row gll16 group
  const int lcol = (((l & 7) ^ lrow) << 3);      // pre-swizzled source col (elems)

  f32x4 acc[8][NFR] = {};
  const int NKT = K >> 6;

  auto stage = [&](int bi, int kt) {
    #pragma unroll
    for (int i = 0; i < 4; ++i) {               // A: rows [wv*32, wv*32+32)
      const int r0 = wv * 32 + i * 8;
      gll16(A + (size_t)(m0 + r0 + lrow) * lda + kt + lcol, (void*)&As[bi][r0 * 64]);
    }
    #pragma unroll
    for (int i = 0; i < BN / 64; ++i) {         // B: rows [wv*(BN/8), +BN/8)
      const int r0 = wv * (BN / 8) + i * 8;
      gll16(B + (size_t)(n0 + r0 + lrow) * K + kt + lcol, (void*)&Bs[bi][r0 * 64]);
    }
  };

  stage(0, 0);

  for (int t = 0; t < NKT; ++t) {
    const int bi = t & 1;
    // previous end-of-iter barrier guarantees buf[bi^1] reads are done (WAR)
    if (t + 1 < NKT) stage(bi ^ 1, (t + 1) * 64);
    __builtin_amdgcn_sched_barrier(0);
    if (t + 1 < NKT) {
      if (BN == 256) asm volatile("s_waitcnt vmcnt(8)" ::: "memory");
      else           asm volatile("s_waitcnt vmcnt(7)" ::: "memory");
    } else {
      asm volatile("s_waitcnt vmcnt(0)" ::: "memory");
    }
    __builtin_amdgcn_s_barrier();                // RAW: tile t visible to all waves
    __builtin_amdgcn_sched_barrier(0);

    const unsigned short* Ab = As[bi];
    const unsigned short* Bb = Bs[bi];
    auto rdA = [&](int m, int kk) -> s16x8 {
      const int row = wm * 128 + m * 16 + lo;
      return *(const s16x8*)&Ab[row * 64 + ((kk * 32 + hi * 8) ^ ((row & 7) << 3))];
    };
    auto rdB = [&](int n, int kk) -> s16x8 {
      const int row = wn * (BN / 4) + n * 16 + lo;
      return *(const s16x8*)&Bb[row * 64 + ((kk * 32 + hi * 8) ^ ((row & 7) << 3))];
    };

    s16x8 a[4][2], b0[2][2], b2[2][2];
    // ---- quadrant (0, lowN): A rows 0-3 + B frags 0-1
    #pragma unroll
    for (int m = 0; m < 4; ++m) { a[m][0] = rdA(m, 0); a[m][1] = rdA(m, 1); }
    #pragma unroll
    for (int n = 0; n < 2; ++n) { b0[n][0] = rdB(n, 0); b0[n][1] = rdB(n, 1); }
    __builtin_amdgcn_s_setprio(1);
    #pragma unroll
    for (int m = 0; m < 4; ++m)
      #pragma unroll
      for (int n = 0; n < 2; ++n) {
        acc[m][n] = mfma_bf16(a[m][0], b0[n][0], acc[m][n]);
        acc[m][n] = mfma_bf16(a[m][1], b0[n][1], acc[m][n]);
      }
    __builtin_amdgcn_s_setprio(0);
    // ---- quadrant (0, hiN): B frags 2.. new
    #pragma unroll
    for (int n = 0; n < NB2; ++n) { b2[n][0] = rdB(n + 2, 0); b2[n][1] = rdB(n + 2, 1); }
    __builtin_amdgcn_s_setprio(1);
    #pragma unroll
    for (int m = 0; m < 4; ++m)
      #pragma unroll
      for (int n = 0; n < NB2; ++n) {
        acc[m][n + 2] = mfma_bf16(a[m][0], b2[n][0], acc[m][n + 2]);
        acc[m][n + 2] = mfma_bf16(a[m][1], b2[n][1], acc[m][n + 2]);
      }
    __builtin_amdgcn_s_setprio(0);
    // ---- quadrant (1, hiN): A rows 4-7 new
    #pragma unroll
    for (int m = 0; m < 4; ++m) { a[m][0] = rdA(m + 4, 0); a[m][1] = rdA(m + 4, 1); }
    __builtin_amdgcn_s_setprio(1);
    #pragma unroll
    for (int m = 0; m < 4; ++m)
      #pragma unroll
      for (int n = 0; n < NB2; ++n) {
        acc[m + 4][n + 2] = mfma_bf16(a[m][0], b2[n][0], acc[m + 4][n + 2]);
        acc[m + 4][n + 2] = mfma_bf16(a[m][1], b2[n][1], acc[m + 4][n + 2]);
      }
    __builtin_amdgcn_s_setprio(0);
    // ---- quadrant (1, lowN): all-reuse
    __builtin_amdgcn_s_setprio(1);
    #pragma unroll
    for (int m = 0; m < 4; ++m)
      #pragma unroll
      for (int n = 0; n < 2; ++n) {
        acc[m + 4][n] = mfma_bf16(a[m][0], b0[n][0], acc[m + 4][n]);
        acc[m + 4][n] = mfma_bf16(a[m][1], b0[n][1], acc[m + 4][n]);
      }
    __builtin_amdgcn_s_setprio(0);
    __builtin_amdgcn_sched_barrier(0);
    __builtin_amdgcn_s_barrier();                // WAR: reads of buf[bi] complete
    __builtin_amdgcn_sched_barrier(0);
  }

  if (MODE == 3) {
    // k_nope -> Ka[bh][s][192] cols 0..127; V -> V^T global [bh][dv][s] (8B packed)
    #pragma unroll
    for (int m = 0; m < 8; ++m)
      #pragma unroll
      for (int n = 0; n < NFR; ++n) {
        const int row0 = m0 + wm * 128 + m * 16 + hi * 4;
        const int col = n0 + wn * (BN / 4) + n * 16 + lo;
        const int hh = col >> 8, cc = col & 255;
        const int bb = row0 >> 11, ss = row0 & 2047;
        if (cc < 128) {
          #pragma unroll
          for (int r = 0; r < 4; ++r)
            ((unsigned short*)Cout)[((size_t)((bb * Hc + hh) * Sc + ss + r)) * DQK + cc] =
                f2bf(acc[m][n][r]);
        } else {
          u16x4 o;
          #pragma unroll
          for (int r = 0; r < 4; ++r) o[r] = f2bf(acc[m][n][r]);
          *(u16x4*)&((unsigned short*)Cout2)[((size_t)((bb * Hc + hh) * DVc + (cc - 128))) * Sc + ss] = o;
        }
      }
  } else {
    #pragma unroll
    for (int m = 0; m < 8; ++m)
      #pragma unroll
      for (int n = 0; n < NFR; ++n)
        #pragma unroll
        for (int r = 0; r < 4; ++r) {
          const int row = m0 + wm * 128 + m * 16 + hi * 4 + r;   // token for MODE 2
          const int col = n0 + wn * (BN / 4) + n * 16 + lo;
          const float v = acc[m][n][r];
          if (MODE == 1) {
            ((float*)Cout)[(size_t)row * N + col] = v;
          } else if (MODE == 0) {
            ((unsigned short*)Cout)[(size_t)row * N + col] = f2bf(v);
          } else {  // MODE 2
            const int hh = col / DQK, dd = col % DQK;
            const int bb = row >> 11, ss = row & 2047;
            ((unsigned short*)Cout)[((size_t)((bb * Hc + hh) * Sc + ss)) * DQK + dd] = f2bf(v);
          }
        }
  }
}

// ---------------------------------------------------------------------------
// RoPE, rope-dims only, merged Q+K kernel.  Each thread owns an 8-wide
// (j, j+32) PAIR (race-free partition of the 64 rope dims).
// ---------------------------------------------------------------------------
DEV void rope_pair8(float pos, int j0, const s16x8& x1, const s16x8& x2,
                    s16x8& o1, s16x8& o2) {
  #pragma unroll
  for (int j = 0; j < 8; ++j) {
    const int jj = j0 + j;                       // 0..31
    const float inv = exp2f(-(float)jj * 0.4152410118f);  // 10000^(-jj/32)
    float sn, cs;
    sincosf(pos * inv, &sn, &cs);
    const float a = bf2f((unsigned short)x1[j]);
    const float c = bf2f((unsigned short)x2[j]);
    o1[j] = f2bf(a * cs - c * sn);
    o2[j] = f2bf(c * cs + a * sn);
  }
}

__global__ __launch_bounds__(256) void rope_qk_k(unsigned short* __restrict__ Qa,
                                                 const unsigned short* __restrict__ kr,
                                                 const int* __restrict__ pos,
                                                 unsigned short* __restrict__ Ka) {
  constexpr int NPAIR = Bc * Hc * Sc * 4;           // 524,288 per side
  int gid = blockIdx.x * 256 + threadIdx.x;
  const bool isQ = gid < NPAIR;
  if (!isQ) gid -= NPAIR;
  const int pr = gid & 3, rowp = gid >> 2;          // rowp = bh*2048+s
  const int j0 = pr * 8;
  const int bh = rowp >> 11, s = rowp & 2047;
  const int token = (bh >> 5) * Sc + s;
  const float p = (float)pos[token];
  if (isQ) {
    unsigned short* base = Qa + (size_t)rowp * DQK + 128;
    s16x8 x1 = *(const s16x8*)&base[j0];
    s16x8 x2 = *(const s16x8*)&base[j0 + 32];
    s16x8 o1, o2;
    rope_pair8(p, j0, x1, x2, o1, o2);
    *(s16x8*)&base[j0] = o1;
    *(s16x8*)&base[j0 + 32] = o2;
  } else {
    const int h = bh & 31;
    const unsigned short* src = kr + (size_t)token * HIDc + h * DRc;  // pitch HIDc
    s16x8 x1 = *(const s16x8*)&src[j0];
    s16x8 x2 = *(const s16x8*)&src[j0 + 32];
    s16x8 o1, o2;
    rope_pair8(p, j0, x1, x2, o1, o2);
    unsigned short* dst = Ka + (size_t)rowp * DQK + 128;
    *(s16x8*)&dst[j0] = o1;
    *(s16x8*)&dst[j0 + 32] = o2;
  }
}

// ---------------------------------------------------------------------------
// Flash attention, swapped-QK^T in-register softmax, 16 q-rows/wave (r12).
// 8 waves = 128 q-rows/block.  LDS 56 KB (Ks 24K + Vs 16K + Ps 16K), all
// single-buffered, K and V both staged by gll16 (pre-swizzled source).
// __launch_bounds__(512,4): ~64 arch VGPR + 32 AGPR -> 2 blocks/CU;
// independent blocks overlap each other's staging drains (m114).
// Softmax max/sum use balanced trees (v_max3-fusable groupings).
// ---------------------------------------------------------------------------
__global__ __launch_bounds__(512, 4) void attn_k(const unsigned short* __restrict__ Q,
                                                 const unsigned short* __restrict__ Kt,
                                                 const unsigned short* __restrict__ Vt,
                                                 unsigned short* __restrict__ O) {
  __shared__ unsigned short Ks[64 * 192];       // 24 KB, swizzled rows
  __shared__ unsigned short Vs[128 * 64];       // 16 KB, V^T [dv][key] swizzled
  __shared__ unsigned short Ps[8][16 * 64];     // 16 KB, per-wave P, pitch 64
  const int bh = blockIdx.x, qblk = blockIdx.y; // bh fastest: same-bh -> same XCD
  const int b = bh >> 5, h = bh & 31;
  const int tid = threadIdx.x, w = tid >> 6, l = tid & 63;
  const int lo = l & 15, hi = l >> 4;
  const int sw = (lo & 7) << 3;                 // Ps row swizzle (row = lo)
  const unsigned short* Qb = Q + (size_t)bh * Sc * DQK;
  const unsigned short* Kb = Kt + (size_t)bh * Sc * DQK;
  const unsigned short* Vb = Vt + (size_t)bh * DVc * Sc;   // V^T [dv][s]
  const int qrow0 = qblk * 128 + w * 16;
  const float c2 = 0.10411759f;                 // (1/sqrt(192)) * log2(e)

  s16x8 qfr[6];                                 // B-frag: q=qrow0+lo, d=dc*32+hi*8
  #pragma unroll
  for (int dc = 0; dc < 6; ++dc)
    qfr[dc] = *(const s16x8*)&Qb[(size_t)(qrow0 + lo) * DQK + dc * 32 + hi * 8];

  f32x4 oacc[8] = {};
  float mrow = -INFINITY;                       // per-lane, q = qrow0+lo (log2 domain)
  float lrow = 0.f;

  auto stageK = [&](int kt) {
    #pragma unroll
    for (int i = 0; i < 3; ++i) {
      const int o = (w * 3 + i) * 1024 + l * 16;   // byte offset in 64x192 tile
      const int rr = o / 384, cc = o % 384;
      const int scc = cc ^ ((rr & 7) << 4);
      gll16(Kb + (size_t)(kt + rr) * DQK + (scc >> 1), (void*)&Ks[(w * 3 + i) * 512]);
    }
  };
  auto stageV = [&](int kt) {
    #pragma unroll
    for (int i = 0; i < 2; ++i) {
      const int dvb = w * 16 + i * 8;              // covers dv [dvb, dvb+8)
      const int dv = dvb + (l >> 3);
      const int ksrc = ((l & 7) ^ (dv & 7)) * 8;   // pre-swizzled source key chunk
      gll16(Vb + (size_t)dv * Sc + kt + ksrc, (void*)&Vs[dvb * 64]);
    }
  };

  constexpr int NT = Sc / 64;   // 32

  for (int t = 0; t < NT; ++t) {
    stageK(t * 64);
    stageV(t * 64);
    asm volatile("s_waitcnt vmcnt(0)" ::: "memory");
    __builtin_amdgcn_s_barrier();                // K/V tile ready
    __builtin_amdgcn_sched_barrier(0);

    // ---- QK^T swapped: sc[cf] = S[key=cf*16+hi*4+r][q=qrow0+lo]
    f32x4 sc[4] = {};
    #pragma unroll
    for (int cf = 0; cf < 4; ++cf) {
      const int krow = cf * 16 + lo;
      #pragma unroll
      for (int dc = 0; dc < 6; ++dc) {
        s16x8 kf = *(const s16x8*)&Ks[(krow * 192 + dc * 32 + hi * 8) ^ ((krow & 7) << 3)];
        sc[cf] = mfma_bf16(kf, qfr[dc], sc[cf]);
      }
    }

    // ---- in-register online softmax (defer-max T13; tree reductions)
    {
      float mq[4];
      #pragma unroll
      for (int cf = 0; cf < 4; ++cf)
        mq[cf] = fmaxf(fmaxf(sc[cf][0], sc[cf][1]), fmaxf(sc[cf][2], sc[cf][3]));
      float mx = fmaxf(fmaxf(mq[0], mq[1]), fmaxf(mq[2], mq[3]));
      mx = fmaxf(mx, __shfl_xor(mx, 16, 64));
      mx = fmaxf(mx, __shfl_xor(mx, 32, 64));
      const float mxl = mx * c2;
      if (!__all(mxl - mrow <= 8.f)) {           // rescale only on real growth
        const float nm = fmaxf(mrow, mxl);
        const float alpha = exp2f(mrow - nm);
        mrow = nm;
        lrow *= alpha;
        #pragma unroll
        for (int r = 0; r < 4; ++r) {
          const float ar = __shfl(alpha, hi * 4 + r, 64);
          #pragma unroll
          for (int dvf = 0; dvf < 8; ++dvf) oacc[dvf][r] *= ar;
        }
      }
      float ps[4];
      #pragma unroll
      for (int cf = 0; cf < 4; ++cf) {
        sc[cf][0] = exp2f(fmaf(sc[cf][0], c2, -mrow));
        sc[cf][1] = exp2f(fmaf(sc[cf][1], c2, -mrow));
        sc[cf][2] = exp2f(fmaf(sc[cf][2], c2, -mrow));
        sc[cf][3] = exp2f(fmaf(sc[cf][3], c2, -mrow));
        ps[cf] = (sc[cf][0] + sc[cf][1]) + (sc[cf][2] + sc[cf][3]);
        const int ka = cf * 16 + hi * 4;
        *(unsigned*)&Ps[w][lo * 64 + ((ka + 0) ^ sw)] = cvt_pk_bf16(sc[cf][0], sc[cf][1]);
        *(unsigned*)&Ps[w][lo * 64 + ((ka + 2) ^ sw)] = cvt_pk_bf16(sc[cf][2], sc[cf][3]);
      }
      float psum = (ps[0] + ps[1]) + (ps[2] + ps[3]);
      psum += __shfl_xor(psum, 16, 64);
      psum += __shfl_xor(psum, 32, 64);
      lrow += psum;
    }

    // ---- PV: pa from Ps (A-frag rows = q), vb = V^T from Vs
    #pragma unroll
    for (int hf = 0; hf < 2; ++hf) {
      s16x8 pa = *(const s16x8*)&Ps[w][lo * 64 + ((hf * 32 + hi * 8) ^ sw)];
      #pragma unroll
      for (int dvf = 0; dvf < 8; ++dvf) {
        const int dv = dvf * 16 + lo;
        s16x8 vb = *(const s16x8*)&Vs[dv * 64 + ((hf * 32 + hi * 8) ^ ((dv & 7) << 3))];
        oacc[dvf] = mfma_bf16(pa, vb, oacc[dvf]);
      }
    }

    __builtin_amdgcn_s_barrier();                // all reads done -> next stage safe
    __builtin_amdgcn_sched_barrier(0);
  }

  // ---- epilogue: O[token][h*128+dv] = oacc / l  (gather l across lanes)
  #pragma unroll
  for (int r = 0; r < 4; ++r) {
    const float linv = 1.f / __shfl(lrow, hi * 4 + r, 64);
    const int q = qrow0 + hi * 4 + r;
    #pragma unroll
    for (int dvf = 0; dvf < 8; ++dvf)
      O[(size_t)(b * Sc + q) * (Hc * DVc) + h * DVc + dvf * 16 + lo] =
          f2bf(oacc[dvf][r] * linv);
  }
}

// ---------------------------------------------------------------------------
extern "C" void kernel_launch(void* const* d_in, const int* in_sizes, int n_in,
                              void* d_out, int out_size, void* d_ws, size_t ws_size,
                              hipStream_t stream) {
  const float* hs      = (const float*)d_in[0];
  const int*   posids  = (const int*)d_in[1];
  const float* qa_w    = (const float*)d_in[2];
  const float* qa_ln   = (const float*)d_in[3];
  const float* qb_w    = (const float*)d_in[4];
  const float* kva_w   = (const float*)d_in[5];
  const float* kva_ln  = (const float*)d_in[6];
  const float* kvb_w   = (const float*)d_in[7];
  const float* kr_w    = (const float*)d_in[8];
  const float* o_w     = (const float*)d_in[9];
  float* out = (float*)d_out;

  // ---- overlaid workspace (237.0 MB) + d_out as pre-o-proj scratch ----
  char* ws = (char*)d_ws;
  const size_t offF = 0;                    // 33,554,432: hs_bf -> attn_o
  const size_t offR = offF + 33554432;      // 35,651,584: cbuf (33.5M used)
  const size_t offD = offR + 35651584;      // 50,331,648: w_qb (18.9M) -> Ka
  const size_t offA = offD + 50331648;      // 67,108,864: kv_vt (33.5M) + w_o (33.5M)
  const size_t offB = offA + 67108864;      // 50,331,648: cw -> Qa

  unsigned short* hs_bf  = (unsigned short*)(ws + offF);
  unsigned short* attn_o = (unsigned short*)(ws + offF);   // after kv_b gemm (pre-attn)
  unsigned short* cbuf   = (unsigned short*)(ws + offR);   // [qa_n | kva_n | kr], pitch 4096
  unsigned short* w_qb   = (unsigned short*)(ws + offD);   // up-front cast; dead pre-kv_b
  unsigned short* Ka     = (unsigned short*)(ws + offD);   // from kv_b + rope (after q_b)
  unsigned short* kv_vt  = (unsigned short*)(ws + offA);   // V^T [bh][dv][s]
  unsigned short* w_o    = (unsigned short*)(ws + offA + 33554432);  // cast up-front
  unsigned short* cw     = (unsigned short*)(ws + offB);   // fused weights [4096][4096]
  unsigned short* Qa     = (unsigned short*)(ws + offB);   // direct from q_b gemm
  unsigned short* w_kvb  = (unsigned short*)d_out;         // d_out scratch (dead till o-proj)

  // 1. merged 7-way cast: hs + [qa|kva|kr] + o_w + qb_w + kvb_w (into d_out scratch)
  {
    const long n_hs  = (long)Tc * HIDc;           // 16,777,216
    const long n_qa  = (long)QRc * HIDc;          //  6,291,456
    const long n_kv  = (long)KVRc * HIDc;         //  2,097,152
    const long n_kr  = (long)Hc * DRc * HIDc;     //  8,388,608
    const long n_o   = (long)HIDc * Hc * DVc;     // 16,777,216
    const long n_qb  = (long)Hc * DQK * QRc;      //  9,437,184
    const long n_kvb = (long)Hc * 256 * KVRc;     //  4,194,304
    const long ntot = n_hs + n_qa + n_kv + n_kr + n_o + n_qb + n_kvb;  // 63,963,136
    cast7_k<<<dim3((unsigned)(ntot / 4 / 256)), dim3(256), 0, stream>>>(
        hs, hs_bf, n_hs,
        qa_w, cw, n_qa,
        kva_w, cw + (size_t)QRc * HIDc, n_kv,
        kr_w, cw + (size_t)(QRc + KVRc) * HIDc, n_kr,
        o_w, w_o, n_o,
        qb_w, w_qb, n_qb,
        kvb_w, w_kvb, n_kvb);
  }

  // 2. fused a-projection GEMM: cbuf[4096][4096] = hs_bf x cw^T  (256 blocks)
  gemm256_bt<0><<<dim3(16 * 16), dim3(512), 0, stream>>>(hs_bf, HIDc, cw,
                                                         (void*)cbuf, nullptr,
                                                         Tc, HIDc, HIDc);

  // 3. merged RMSNorms in place on pitched columns (q rows, then kv rows)
  rmsnorm2_k<<<dim3(2 * Tc), dim3(256), 0, stream>>>(cbuf, qa_ln, kva_ln);

  // 4. q_b proj -> Qa layout directly.  BN=192 (head-aligned): grid 512 = 2 full rounds
  gemm256_bt<2, 192><<<dim3(16 * 32), dim3(512), 0, stream>>>(cbuf, HIDc, w_qb,
                                                              (void*)Qa, nullptr,
                                                              Tc, Hc * DQK, QRc);

  // 5. kv_b proj -> k_nope into Ka, V^T into kv_vt [bh][dv][s] (weights from d_out scratch)
  gemm256_bt<3><<<dim3(16 * 32), dim3(512), 0, stream>>>(cbuf + QRc, HIDc, w_kvb,
                                                         (void*)Ka, (void*)kv_vt,
                                                         Tc, Hc * 256, KVRc);

  // 6. merged RoPE (Q in-place, K from cbuf kr -> Ka rope dims)
  {
    const int npair2 = 2 * Bc * Hc * Sc * 4;   // 1,048,576
    rope_qk_k<<<dim3(npair2 / 256), dim3(256), 0, stream>>>(Qa, cbuf + QRc + KVRc,
                                                            posids, Ka);
  }

  // 7. attention: 128 q-rows/block, grid (64 bh, 16 qblk); bh fastest for XCD/L2
  attn_k<<<dim3(Bc * Hc, Sc / 128), dim3(512), 0, stream>>>(Qa, Ka, kv_vt, attn_o);

  // 8. output projection -> fp32 d_out (overwrites the w_kvb scratch; w_o in ws)
  gemm256_bt<1><<<dim3(16 * 16), dim3(512), 0, stream>>>(attn_o, Hc * DVc, w_o,
                                                         (void*)out, nullptr,
                                                         Tc, HIDc, Hc * DVc);

  (void)in_sizes; (void)n_in; (void)out_size; (void)ws_size;
}

// Round 19
// 718.384 us; speedup vs baseline: 1.0238x; 1.0238x over previous
//
#include <hip/hip_runtime.h>
#include <hip/hip_bf16.h>
#include <math.h>

// ---------------------------------------------------------------------------
// DeepSeekV3 MLA forward, bf16 MFMA pipeline.  Workspace: 237.0 MB (overlaid,
// plus d_out used as pre-o-proj scratch for the kv_b weight cast).
// B=2, S=2048, H=32, DN=128, DR=64, DV=128, HID=4096, QR=1536, KVR=512
// Fusions: q_a+kv_a+k_rope in one 4096^3 GEMM; q_b GEMM (BN=192, head-aligned)
// writes Qa layout; kv_b GEMM splits k_nope->Ka / V^T->global; RoPE rope-dims.
// One 7-way up-front cast (all weights + hs).  GEMM loop: 2 barriers/iter.
// Attention (r12/r17 proven): 16 q-rows/wave, 56 KB LDS, single-buffered K/V
// via gll16, 2 blocks/CU; sequential softmax reductions (r18 tree regressed).
// ---------------------------------------------------------------------------

typedef __attribute__((ext_vector_type(8))) short s16x8;   // 8 x bf16 (4 VGPR)
typedef __attribute__((ext_vector_type(4))) float f32x4;
typedef __attribute__((ext_vector_type(4))) unsigned short u16x4;

#define DEV __device__ __forceinline__

constexpr int Bc = 2, Sc = 2048, Tc = Bc * Sc;     // tokens = 4096
constexpr int Hc = 32, DNc = 128, DRc = 64, DVc = 128;
constexpr int HIDc = 4096, QRc = 1536, KVRc = 512;
constexpr int DQK = DNc + DRc;                      // 192

DEV unsigned short f2bf(float f) {
  unsigned u = __float_as_uint(f);
  return (unsigned short)((u + 0x7fffu + ((u >> 16) & 1u)) >> 16);
}
DEV float bf2f(unsigned short u) { return __uint_as_float(((unsigned)u) << 16); }

DEV void gll16(const void* g, void* l) {
  __builtin_amdgcn_global_load_lds((const __attribute__((address_space(1))) void*)g,
                                   (__attribute__((address_space(3))) void*)l, 16, 0, 0);
}
DEV f32x4 mfma_bf16(s16x8 a, s16x8 b, f32x4 c) {
  return __builtin_amdgcn_mfma_f32_16x16x32_bf16(a, b, c, 0, 0, 0);
}
DEV unsigned cvt_pk_bf16(float a, float b) {     // lo=bf16(a), hi=bf16(b)
  unsigned r;
  asm("v_cvt_pk_bf16_f32 %0, %1, %2" : "=v"(r) : "v"(a), "v"(b));
  return r;
}

// ---------------------------------------------------------------------------
// casts: 7-way merged variant covering every fp32->bf16 conversion up front
// ---------------------------------------------------------------------------
DEV void cast4(const float* src, unsigned short* dst, long i) {
  float4 v = *(const float4*)(src + i);
  u16x4 o;
  o.x = f2bf(v.x); o.y = f2bf(v.y); o.z = f2bf(v.z); o.w = f2bf(v.w);
  *(u16x4*)(dst + i) = o;
}

__global__ __launch_bounds__(256) void cast7_k(const float* s0, unsigned short* d0, long n0,
                                               const float* s1, unsigned short* d1, long n1,
                                               const float* s2, unsigned short* d2, long n2,
                                               const float* s3, unsigned short* d3, long n3,
                                               const float* s4, unsigned short* d4, long n4,
                                               const float* s5, unsigned short* d5, long n5,
                                               const float* s6, unsigned short* d6, long n6) {
  long i = ((long)blockIdx.x * 256 + threadIdx.x) * 4;
  if (i < n0) { cast4(s0, d0, i); return; }  i -= n0;
  if (i < n1) { cast4(s1, d1, i); return; }  i -= n1;
  if (i < n2) { cast4(s2, d2, i); return; }  i -= n2;
  if (i < n3) { cast4(s3, d3, i); return; }  i -= n3;
  if (i < n4) { cast4(s4, d4, i); return; }  i -= n4;
  if (i < n5) { cast4(s5, d5, i); return; }  i -= n5;
  if (i < n6) { cast4(s6, d6, i); }
}

// ---------------------------------------------------------------------------
// RMSNorm helper + merged kernel (q rows then kv rows, pitch HIDc)
// ---------------------------------------------------------------------------
template <int COLS>
DEV void rms_row(unsigned short* p, const float* __restrict__ w, float* sred) {
  float ss = 0.f;
  for (int c = threadIdx.x * 8; c < COLS; c += 2048) {
    s16x8 v = *(const s16x8*)&p[c];
    #pragma unroll
    for (int j = 0; j < 8; ++j) { const float f = bf2f((unsigned short)v[j]); ss += f * f; }
  }
  #pragma unroll
  for (int off = 1; off < 64; off <<= 1) ss += __shfl_xor(ss, off, 64);
  if ((threadIdx.x & 63) == 0) sred[threadIdx.x >> 6] = ss;
  __syncthreads();
  const float inv = rsqrtf((sred[0] + sred[1] + sred[2] + sred[3]) / (float)COLS + 1e-6f);
  for (int c = threadIdx.x * 8; c < COLS; c += 2048) {
    s16x8 v = *(const s16x8*)&p[c];
    s16x8 o;
    #pragma unroll
    for (int j = 0; j < 8; ++j)
      o[j] = (short)f2bf(bf2f((unsigned short)v[j]) * inv * w[c + j]);
    *(s16x8*)&p[c] = o;
  }
}

__global__ __launch_bounds__(256) void rmsnorm2_k(unsigned short* __restrict__ cbuf,
                                                  const float* __restrict__ wq,
                                                  const float* __restrict__ wkv) {
  __shared__ float sred[4];
  const int bid = blockIdx.x;
  if (bid < Tc) rms_row<QRc>(cbuf + (size_t)bid * HIDc, wq, sred);
  else          rms_row<KVRc>(cbuf + (size_t)(bid - Tc) * HIDc + QRc, wkv, sred);
}

// ---------------------------------------------------------------------------
// GEMM: C[M,N] = A[M,K](bf16, row pitch lda) * B[N,K]^T(bf16, pitch K).
// BM=256 x BN(256 or 192) tile, BK=64.  512 thr = 8 waves (2M x 4N).
// Counted-vmcnt double-buffer.  TWO barriers per iter (RAW post-vmcnt + WAR
// end); quadrant groups share one K-tile buffer -> no inner barriers.
// LDS swizzle via pre-swizzled gll16 SOURCE, XOR (row&7)<<3.
// MODE: 0 = bf16 linear, 1 = f32 linear,
//       2 = Qa layout   (row=token, col=h*192+d  -> Qa[bh][s][192])
//       3 = kv split    (col=h*256+c: c<128 -> Ka[bh][s][192];
//                        c>=128 -> V^T global [bh][dv][s], 8B packed stores)
// ---------------------------------------------------------------------------
template <int MODE, int BN = 256>
__global__ __launch_bounds__(512, 2) void gemm256_bt(const unsigned short* __restrict__ A,
                                                     int lda,
                                                     const unsigned short* __restrict__ B,
                                                     void* __restrict__ Cout,
                                                     void* __restrict__ Cout2,
                                                     int M, int N, int K) {
  constexpr int NFR = BN / 64;                  // n-frags per wave (4 or 3)
  constexpr int NB2 = NFR - 2;                  // frags in the "b2" group (2 or 1)
  __shared__ unsigned short As[2][256 * 64];    // 64 KB
  __shared__ unsigned short Bs[2][BN * 64];     // 64 or 48 KB
  const int tid = threadIdx.x;
  const int wv = tid >> 6, l = tid & 63;
  const int lo = l & 15, hi = l >> 4;
  const int wm = wv >> 2, wn = wv & 3;          // wave grid 2 x 4
  // bijective XCD swizzle (m204)
  const int nbx = N / BN;
  const int nwg = (M >> 8) * nbx;
  const int orig = blockIdx.x;
  const int q8 = nwg >> 3, r8 = nwg & 7, xc = orig & 7, o8 = orig >> 3;
  const int wg = (xc < r8 ? xc * (q8 + 1) : r8 * (q8 + 1) + (xc - r8) * q8) + o8;
  const int bx = wg % nbx, by = wg / nbx;
  const int m0 = by * 256, n0 = bx * BN;
  const int lrow = l >> 3;                       // row within 8-row gll16 group
  const int lcol = (((l & 7) ^ lrow) << 3);      // pre-swizzled source col (elems)

  f32x4 acc[8][NFR] = {};
  const int NKT = K >> 6;

  auto stage = [&](int bi, int kt) {
    #pragma unroll
    for (int i = 0; i < 4; ++i) {               // A: rows [wv*32, wv*32+32)
      const int r0 = wv * 32 + i * 8;
      gll16(A + (size_t)(m0 + r0 + lrow) * lda + kt + lcol, (void*)&As[bi][r0 * 64]);
    }
    #pragma unroll
    for (int i = 0; i < BN / 64; ++i) {         // B: rows [wv*(BN/8), +BN/8)
      const int r0 = wv * (BN / 8) + i * 8;
      gll16(B + (size_t)(n0 + r0 + lrow) * K + kt + lcol, (void*)&Bs[bi][r0 * 64]);
    }
  };

  stage(0, 0);

  for (int t = 0; t < NKT; ++t) {
    const int bi = t & 1;
    // previous end-of-iter barrier guarantees buf[bi^1] reads are done (WAR)
    if (t + 1 < NKT) stage(bi ^ 1, (t + 1) * 64);
    __builtin_amdgcn_sched_barrier(0);
    if (t + 1 < NKT) {
      if (BN == 256) asm volatile("s_waitcnt vmcnt(8)" ::: "memory");
      else           asm volatile("s_waitcnt vmcnt(7)" ::: "memory");
    } else {
      asm volatile("s_waitcnt vmcnt(0)" ::: "memory");
    }
    __builtin_amdgcn_s_barrier();                // RAW: tile t visible to all waves
    __builtin_amdgcn_sched_barrier(0);

    const unsigned short* Ab = As[bi];
    const unsigned short* Bb = Bs[bi];
    auto rdA = [&](int m, int kk) -> s16x8 {
      const int row = wm * 128 + m * 16 + lo;
      return *(const s16x8*)&Ab[row * 64 + ((kk * 32 + hi * 8) ^ ((row & 7) << 3))];
    };
    auto rdB = [&](int n, int kk) -> s16x8 {
      const int row = wn * (BN / 4) + n * 16 + lo;
      return *(const s16x8*)&Bb[row * 64 + ((kk * 32 + hi * 8) ^ ((row & 7) << 3))];
    };

    s16x8 a[4][2], b0[2][2], b2[2][2];
    // ---- quadrant (0, lowN): A rows 0-3 + B frags 0-1
    #pragma unroll
    for (int m = 0; m < 4; ++m) { a[m][0] = rdA(m, 0); a[m][1] = rdA(m, 1); }
    #pragma unroll
    for (int n = 0; n < 2; ++n) { b0[n][0] = rdB(n, 0); b0[n][1] = rdB(n, 1); }
    __builtin_amdgcn_s_setprio(1);
    #pragma unroll
    for (int m = 0; m < 4; ++m)
      #pragma unroll
      for (int n = 0; n < 2; ++n) {
        acc[m][n] = mfma_bf16(a[m][0], b0[n][0], acc[m][n]);
        acc[m][n] = mfma_bf16(a[m][1], b0[n][1], acc[m][n]);
      }
    __builtin_amdgcn_s_setprio(0);
    // ---- quadrant (0, hiN): B frags 2.. new
    #pragma unroll
    for (int n = 0; n < NB2; ++n) { b2[n][0] = rdB(n + 2, 0); b2[n][1] = rdB(n + 2, 1); }
    __builtin_amdgcn_s_setprio(1);
    #pragma unroll
    for (int m = 0; m < 4; ++m)
      #pragma unroll
      for (int n = 0; n < NB2; ++n) {
        acc[m][n + 2] = mfma_bf16(a[m][0], b2[n][0], acc[m][n + 2]);
        acc[m][n + 2] = mfma_bf16(a[m][1], b2[n][1], acc[m][n + 2]);
      }
    __builtin_amdgcn_s_setprio(0);
    // ---- quadrant (1, hiN): A rows 4-7 new
    #pragma unroll
    for (int m = 0; m < 4; ++m) { a[m][0] = rdA(m + 4, 0); a[m][1] = rdA(m + 4, 1); }
    __builtin_amdgcn_s_setprio(1);
    #pragma unroll
    for (int m = 0; m < 4; ++m)
      #pragma unroll
      for (int n = 0; n < NB2; ++n) {
        acc[m + 4][n + 2] = mfma_bf16(a[m][0], b2[n][0], acc[m + 4][n + 2]);
        acc[m + 4][n + 2] = mfma_bf16(a[m][1], b2[n][1], acc[m + 4][n + 2]);
      }
    __builtin_amdgcn_s_setprio(0);
    // ---- quadrant (1, lowN): all-reuse
    __builtin_amdgcn_s_setprio(1);
    #pragma unroll
    for (int m = 0; m < 4; ++m)
      #pragma unroll
      for (int n = 0; n < 2; ++n) {
        acc[m + 4][n] = mfma_bf16(a[m][0], b0[n][0], acc[m + 4][n]);
        acc[m + 4][n] = mfma_bf16(a[m][1], b0[n][1], acc[m + 4][n]);
      }
    __builtin_amdgcn_s_setprio(0);
    __builtin_amdgcn_sched_barrier(0);
    __builtin_amdgcn_s_barrier();                // WAR: reads of buf[bi] complete
    __builtin_amdgcn_sched_barrier(0);
  }

  if (MODE == 3) {
    // k_nope -> Ka[bh][s][192] cols 0..127; V -> V^T global [bh][dv][s] (8B packed)
    #pragma unroll
    for (int m = 0; m < 8; ++m)
      #pragma unroll
      for (int n = 0; n < NFR; ++n) {
        const int row0 = m0 + wm * 128 + m * 16 + hi * 4;
        const int col = n0 + wn * (BN / 4) + n * 16 + lo;
        const int hh = col >> 8, cc = col & 255;
        const int bb = row0 >> 11, ss = row0 & 2047;
        if (cc < 128) {
          #pragma unroll
          for (int r = 0; r < 4; ++r)
            ((unsigned short*)Cout)[((size_t)((bb * Hc + hh) * Sc + ss + r)) * DQK + cc] =
                f2bf(acc[m][n][r]);
        } else {
          u16x4 o;
          #pragma unroll
          for (int r = 0; r < 4; ++r) o[r] = f2bf(acc[m][n][r]);
          *(u16x4*)&((unsigned short*)Cout2)[((size_t)((bb * Hc + hh) * DVc + (cc - 128))) * Sc + ss] = o;
        }
      }
  } else {
    #pragma unroll
    for (int m = 0; m < 8; ++m)
      #pragma unroll
      for (int n = 0; n < NFR; ++n)
        #pragma unroll
        for (int r = 0; r < 4; ++r) {
          const int row = m0 + wm * 128 + m * 16 + hi * 4 + r;   // token for MODE 2
          const int col = n0 + wn * (BN / 4) + n * 16 + lo;
          const float v = acc[m][n][r];
          if (MODE == 1) {
            ((float*)Cout)[(size_t)row * N + col] = v;
          } else if (MODE == 0) {
            ((unsigned short*)Cout)[(size_t)row * N + col] = f2bf(v);
          } else {  // MODE 2
            const int hh = col / DQK, dd = col % DQK;
            const int bb = row >> 11, ss = row & 2047;
            ((unsigned short*)Cout)[((size_t)((bb * Hc + hh) * Sc + ss)) * DQK + dd] = f2bf(v);
          }
        }
  }
}

// ---------------------------------------------------------------------------
// RoPE, rope-dims only, merged Q+K kernel.  Each thread owns an 8-wide
// (j, j+32) PAIR (race-free partition of the 64 rope dims).
// ---------------------------------------------------------------------------
DEV void rope_pair8(float pos, int j0, const s16x8& x1, const s16x8& x2,
                    s16x8& o1, s16x8& o2) {
  #pragma unroll
  for (int j = 0; j < 8; ++j) {
    const int jj = j0 + j;                       // 0..31
    const float inv = exp2f(-(float)jj * 0.4152410118f);  // 10000^(-jj/32)
    float sn, cs;
    sincosf(pos * inv, &sn, &cs);
    const float a = bf2f((unsigned short)x1[j]);
    const float c = bf2f((unsigned short)x2[j]);
    o1[j] = f2bf(a * cs - c * sn);
    o2[j] = f2bf(c * cs + a * sn);
  }
}

__global__ __launch_bounds__(256) void rope_qk_k(unsigned short* __restrict__ Qa,
                                                 const unsigned short* __restrict__ kr,
                                                 const int* __restrict__ pos,
                                                 unsigned short* __restrict__ Ka) {
  constexpr int NPAIR = Bc * Hc * Sc * 4;           // 524,288 per side
  int gid = blockIdx.x * 256 + threadIdx.x;
  const bool isQ = gid < NPAIR;
  if (!isQ) gid -= NPAIR;
  const int pr = gid & 3, rowp = gid >> 2;          // rowp = bh*2048+s
  const int j0 = pr * 8;
  const int bh = rowp >> 11, s = rowp & 2047;
  const int token = (bh >> 5) * Sc + s;
  const float p = (float)pos[token];
  if (isQ) {
    unsigned short* base = Qa + (size_t)rowp * DQK + 128;
    s16x8 x1 = *(const s16x8*)&base[j0];
    s16x8 x2 = *(const s16x8*)&base[j0 + 32];
    s16x8 o1, o2;
    rope_pair8(p, j0, x1, x2, o1, o2);
    *(s16x8*)&base[j0] = o1;
    *(s16x8*)&base[j0 + 32] = o2;
  } else {
    const int h = bh & 31;
    const unsigned short* src = kr + (size_t)token * HIDc + h * DRc;  // pitch HIDc
    s16x8 x1 = *(const s16x8*)&src[j0];
    s16x8 x2 = *(const s16x8*)&src[j0 + 32];
    s16x8 o1, o2;
    rope_pair8(p, j0, x1, x2, o1, o2);
    unsigned short* dst = Ka + (size_t)rowp * DQK + 128;
    *(s16x8*)&dst[j0] = o1;
    *(s16x8*)&dst[j0 + 32] = o2;
  }
}

// ---------------------------------------------------------------------------
// Flash attention, swapped-QK^T in-register softmax, 16 q-rows/wave (r12/r17).
// 8 waves = 128 q-rows/block.  LDS 56 KB (Ks 24K + Vs 16K + Ps 16K), all
// single-buffered, K and V both staged by gll16 (pre-swizzled source).
// __launch_bounds__(512,4): ~64 arch VGPR + 32 AGPR -> 2 blocks/CU;
// independent blocks overlap each other's staging drains (m114).
// Sequential softmax reductions (r18 tree-shaping regressed -17us; reverted).
// ---------------------------------------------------------------------------
__global__ __launch_bounds__(512, 4) void attn_k(const unsigned short* __restrict__ Q,
                                                 const unsigned short* __restrict__ Kt,
                                                 const unsigned short* __restrict__ Vt,
                                                 unsigned short* __restrict__ O) {
  __shared__ unsigned short Ks[64 * 192];       // 24 KB, swizzled rows
  __shared__ unsigned short Vs[128 * 64];       // 16 KB, V^T [dv][key] swizzled
  __shared__ unsigned short Ps[8][16 * 64];     // 16 KB, per-wave P, pitch 64
  const int bh = blockIdx.x, qblk = blockIdx.y; // bh fastest: same-bh -> same XCD
  const int b = bh >> 5, h = bh & 31;
  const int tid = threadIdx.x, w = tid >> 6, l = tid & 63;
  const int lo = l & 15, hi = l >> 4;
  const int sw = (lo & 7) << 3;                 // Ps row swizzle (row = lo)
  const unsigned short* Qb = Q + (size_t)bh * Sc * DQK;
  const unsigned short* Kb = Kt + (size_t)bh * Sc * DQK;
  const unsigned short* Vb = Vt + (size_t)bh * DVc * Sc;   // V^T [dv][s]
  const int qrow0 = qblk * 128 + w * 16;
  const float c2 = 0.10411759f;                 // (1/sqrt(192)) * log2(e)

  s16x8 qfr[6];                                 // B-frag: q=qrow0+lo, d=dc*32+hi*8
  #pragma unroll
  for (int dc = 0; dc < 6; ++dc)
    qfr[dc] = *(const s16x8*)&Qb[(size_t)(qrow0 + lo) * DQK + dc * 32 + hi * 8];

  f32x4 oacc[8] = {};
  float mrow = -INFINITY;                       // per-lane, q = qrow0+lo (log2 domain)
  float lrow = 0.f;

  auto stageK = [&](int kt) {
    #pragma unroll
    for (int i = 0; i < 3; ++i) {
      const int o = (w * 3 + i) * 1024 + l * 16;   // byte offset in 64x192 tile
      const int rr = o / 384, cc = o % 384;
      const int scc = cc ^ ((rr & 7) << 4);
      gll16(Kb + (size_t)(kt + rr) * DQK + (scc >> 1), (void*)&Ks[(w * 3 + i) * 512]);
    }
  };
  auto stageV = [&](int kt) {
    #pragma unroll
    for (int i = 0; i < 2; ++i) {
      const int dvb = w * 16 + i * 8;              // covers dv [dvb, dvb+8)
      const int dv = dvb + (l >> 3);
      const int ksrc = ((l & 7) ^ (dv & 7)) * 8;   // pre-swizzled source key chunk
      gll16(Vb + (size_t)dv * Sc + kt + ksrc, (void*)&Vs[dvb * 64]);
    }
  };

  constexpr int NT = Sc / 64;   // 32

  for (int t = 0; t < NT; ++t) {
    stageK(t * 64);
    stageV(t * 64);
    asm volatile("s_waitcnt vmcnt(0)" ::: "memory");
    __builtin_amdgcn_s_barrier();                // K/V tile ready
    __builtin_amdgcn_sched_barrier(0);

    // ---- QK^T swapped: sc[cf] = S[key=cf*16+hi*4+r][q=qrow0+lo]
    f32x4 sc[4] = {};
    #pragma unroll
    for (int cf = 0; cf < 4; ++cf) {
      const int krow = cf * 16 + lo;
      #pragma unroll
      for (int dc = 0; dc < 6; ++dc) {
        s16x8 kf = *(const s16x8*)&Ks[(krow * 192 + dc * 32 + hi * 8) ^ ((krow & 7) << 3)];
        sc[cf] = mfma_bf16(kf, qfr[dc], sc[cf]);
      }
    }

    // ---- in-register online softmax (defer-max, T13)
    {
      float mx = sc[0][0];
      #pragma unroll
      for (int cf = 0; cf < 4; ++cf)
        #pragma unroll
        for (int r = 0; r < 4; ++r) mx = fmaxf(mx, sc[cf][r]);
      mx = fmaxf(mx, __shfl_xor(mx, 16, 64));
      mx = fmaxf(mx, __shfl_xor(mx, 32, 64));
      const float mxl = mx * c2;
      if (!__all(mxl - mrow <= 8.f)) {           // rescale only on real growth
        const float nm = fmaxf(mrow, mxl);
        const float alpha = exp2f(mrow - nm);
        mrow = nm;
        lrow *= alpha;
        #pragma unroll
        for (int r = 0; r < 4; ++r) {
          const float ar = __shfl(alpha, hi * 4 + r, 64);
          #pragma unroll
          for (int dvf = 0; dvf < 8; ++dvf) oacc[dvf][r] *= ar;
        }
      }
      float psum = 0.f;
      #pragma unroll
      for (int cf = 0; cf < 4; ++cf) {
        sc[cf][0] = exp2f(fmaf(sc[cf][0], c2, -mrow));
        sc[cf][1] = exp2f(fmaf(sc[cf][1], c2, -mrow));
        sc[cf][2] = exp2f(fmaf(sc[cf][2], c2, -mrow));
        sc[cf][3] = exp2f(fmaf(sc[cf][3], c2, -mrow));
        psum += (sc[cf][0] + sc[cf][1]) + (sc[cf][2] + sc[cf][3]);
        const int ka = cf * 16 + hi * 4;
        *(unsigned*)&Ps[w][lo * 64 + ((ka + 0) ^ sw)] = cvt_pk_bf16(sc[cf][0], sc[cf][1]);
        *(unsigned*)&Ps[w][lo * 64 + ((ka + 2) ^ sw)] = cvt_pk_bf16(sc[cf][2], sc[cf][3]);
      }
      psum += __shfl_xor(psum, 16, 64);
      psum += __shfl_xor(psum, 32, 64);
      lrow += psum;
    }

    // ---- PV: pa from Ps (A-frag rows = q), vb = V^T from Vs
    #pragma unroll
    for (int hf = 0; hf < 2; ++hf) {
      s16x8 pa = *(const s16x8*)&Ps[w][lo * 64 + ((hf * 32 + hi * 8) ^ sw)];
      #pragma unroll
      for (int dvf = 0; dvf < 8; ++dvf) {
        const int dv = dvf * 16 + lo;
        s16x8 vb = *(const s16x8*)&Vs[dv * 64 + ((hf * 32 + hi * 8) ^ ((dv & 7) << 3))];
        oacc[dvf] = mfma_bf16(pa, vb, oacc[dvf]);
      }
    }

    __builtin_amdgcn_s_barrier();                // all reads done -> next stage safe
    __builtin_amdgcn_sched_barrier(0);
  }

  // ---- epilogue: O[token][h*128+dv] = oacc / l  (gather l across lanes)
  #pragma unroll
  for (int r = 0; r < 4; ++r) {
    const float linv = 1.f / __shfl(lrow, hi * 4 + r, 64);
    const int q = qrow0 + hi * 4 + r;
    #pragma unroll
    for (int dvf = 0; dvf < 8; ++dvf)
      O[(size_t)(b * Sc + q) * (Hc * DVc) + h * DVc + dvf * 16 + lo] =
          f2bf(oacc[dvf][r] * linv);
  }
}

// ---------------------------------------------------------------------------
extern "C" void kernel_launch(void* const* d_in, const int* in_sizes, int n_in,
                              void* d_out, int out_size, void* d_ws, size_t ws_size,
                              hipStream_t stream) {
  const float* hs      = (const float*)d_in[0];
  const int*   posids  = (const int*)d_in[1];
  const float* qa_w    = (const float*)d_in[2];
  const float* qa_ln   = (const float*)d_in[3];
  const float* qb_w    = (const float*)d_in[4];
  const float* kva_w   = (const float*)d_in[5];
  const float* kva_ln  = (const float*)d_in[6];
  const float* kvb_w   = (const float*)d_in[7];
  const float* kr_w    = (const float*)d_in[8];
  const float* o_w     = (const float*)d_in[9];
  float* out = (float*)d_out;

  // ---- overlaid workspace (237.0 MB) + d_out as pre-o-proj scratch ----
  char* ws = (char*)d_ws;
  const size_t offF = 0;                    // 33,554,432: hs_bf -> attn_o
  const size_t offR = offF + 33554432;      // 35,651,584: cbuf (33.5M used)
  const size_t offD = offR + 35651584;      // 50,331,648: w_qb (18.9M) -> Ka
  const size_t offA = offD + 50331648;      // 67,108,864: kv_vt (33.5M) + w_o (33.5M)
  const size_t offB = offA + 67108864;      // 50,331,648: cw -> Qa

  unsigned short* hs_bf  = (unsigned short*)(ws + offF);
  unsigned short* attn_o = (unsigned short*)(ws + offF);   // after kv_b gemm (pre-attn)
  unsigned short* cbuf   = (unsigned short*)(ws + offR);   // [qa_n | kva_n | kr], pitch 4096
  unsigned short* w_qb   = (unsigned short*)(ws + offD);   // up-front cast; dead pre-kv_b
  unsigned short* Ka     = (unsigned short*)(ws + offD);   // from kv_b + rope (after q_b)
  unsigned short* kv_vt  = (unsigned short*)(ws + offA);   // V^T [bh][dv][s]
  unsigned short* w_o    = (unsigned short*)(ws + offA + 33554432);  // cast up-front
  unsigned short* cw     = (unsigned short*)(ws + offB);   // fused weights [4096][4096]
  unsigned short* Qa     = (unsigned short*)(ws + offB);   // direct from q_b gemm
  unsigned short* w_kvb  = (unsigned short*)d_out;         // d_out scratch (dead till o-proj)

  // 1. merged 7-way cast: hs + [qa|kva|kr] + o_w + qb_w + kvb_w (into d_out scratch)
  {
    const long n_hs  = (long)Tc * HIDc;           // 16,777,216
    const long n_qa  = (long)QRc * HIDc;          //  6,291,456
    const long n_kv  = (long)KVRc * HIDc;         //  2,097,152
    const long n_kr  = (long)Hc * DRc * HIDc;     //  8,388,608
    const long n_o   = (long)HIDc * Hc * DVc;     // 16,777,216
    const long n_qb  = (long)Hc * DQK * QRc;      //  9,437,184
    const long n_kvb = (long)Hc * 256 * KVRc;     //  4,194,304
    const long ntot = n_hs + n_qa + n_kv + n_kr + n_o + n_qb + n_kvb;  // 63,963,136
    cast7_k<<<dim3((unsigned)(ntot / 4 / 256)), dim3(256), 0, stream>>>(
        hs, hs_bf, n_hs,
        qa_w, cw, n_qa,
        kva_w, cw + (size_t)QRc * HIDc, n_kv,
        kr_w, cw + (size_t)(QRc + KVRc) * HIDc, n_kr,
        o_w, w_o, n_o,
        qb_w, w_qb, n_qb,
        kvb_w, w_kvb, n_kvb);
  }

  // 2. fused a-projection GEMM: cbuf[4096][4096] = hs_bf x cw^T  (256 blocks)
  gemm256_bt<0><<<dim3(16 * 16), dim3(512), 0, stream>>>(hs_bf, HIDc, cw,
                                                         (void*)cbuf, nullptr,
                                                         Tc, HIDc, HIDc);

  // 3. merged RMSNorms in place on pitched columns (q rows, then kv rows)
  rmsnorm2_k<<<dim3(2 * Tc), dim3(256), 0, stream>>>(cbuf, qa_ln, kva_ln);

  // 4. q_b proj -> Qa layout directly.  BN=192 (head-aligned): grid 512 = 2 full rounds
  gemm256_bt<2, 192><<<dim3(16 * 32), dim3(512), 0, stream>>>(cbuf, HIDc, w_qb,
                                                              (void*)Qa, nullptr,
                                                              Tc, Hc * DQK, QRc);

  // 5. kv_b proj -> k_nope into Ka, V^T into kv_vt [bh][dv][s] (weights from d_out scratch)
  gemm256_bt<3><<<dim3(16 * 32), dim3(512), 0, stream>>>(cbuf + QRc, HIDc, w_kvb,
                                                         (void*)Ka, (void*)kv_vt,
                                                         Tc, Hc * 256, KVRc);

  // 6. merged RoPE (Q in-place, K from cbuf kr -> Ka rope dims)
  {
    const int npair2 = 2 * Bc * Hc * Sc * 4;   // 1,048,576
    rope_qk_k<<<dim3(npair2 / 256), dim3(256), 0, stream>>>(Qa, cbuf + QRc + KVRc,
                                                            posids, Ka);
  }

  // 7. attention: 128 q-rows/block, grid (64 bh, 16 qblk); bh fastest for XCD/L2
  attn_k<<<dim3(Bc * Hc, Sc / 128), dim3(512), 0, stream>>>(Qa, Ka, kv_vt, attn_o);

  // 8. output projection -> fp32 d_out (overwrites the w_kvb scratch; w_o in ws)
  gemm256_bt<1><<<dim3(16 * 16), dim3(512), 0, stream>>>(attn_o, Hc * DVc, w_o,
                                                         (void*)out, nullptr,
                                                         Tc, HIDc, Hc * DVc);

  (void)in_sizes; (void)n_in; (void)out_size; (void)ws_size;
}